// Round 1
// baseline (479.950 us; speedup 1.0000x reference)
//
#include <hip/hip_runtime.h>

// ---------- constants ----------
// B=16, D=256, L=256, T=1000, K=3, DW=4, DC=2, CH=8

__device__ __forceinline__ float bf2f(unsigned short h) {
  return __uint_as_float(((unsigned int)h) << 16);
}
__device__ __forceinline__ unsigned short f2bf(float f) {
  unsigned int u = __float_as_uint(f);
  u = (u + 0x7FFFu + ((u >> 16) & 1u)) >> 16;
  return (unsigned short)u;
}
__device__ __forceinline__ float swishf(float x) {
  return x / (1.f + expf(-x));
}

// ---------- K1: inclusive scan of durations -> sk, frame_len ----------
__global__ __launch_bounds__(256) void k_scan(const float* __restrict__ dur,
                                              float* __restrict__ sk,
                                              int* __restrict__ frame_len) {
  int b = blockIdx.x, l = threadIdx.x;
  __shared__ float s[256];
  float d = dur[b * 256 + l];
  s[l] = d;
  __syncthreads();
  for (int off = 1; off < 256; off <<= 1) {
    float v = (l >= off) ? s[l - off] : 0.f;
    __syncthreads();
    s[l] += v;
    __syncthreads();
  }
  sk[b * 256 + l] = s[l] - d;
  if (l == 255) {
    int fl = (int)rintf(s[255]);
    fl = min(max(fl, 0), 1000);
    frame_len[b] = fl;
  }
}

// ---------- K2: fold proj into conv: M[br][ch*3+k][d], bK[br][ch*3+k] ----------
__global__ __launch_bounds__(256) void k_fold(const float* __restrict__ cvWw,
                                              const float* __restrict__ pjWw,
                                              const float* __restrict__ pjbw,
                                              const float* __restrict__ cvWc,
                                              const float* __restrict__ pjWc,
                                              const float* __restrict__ pjbc,
                                              float* __restrict__ M,
                                              float* __restrict__ bK) {
  int x = blockIdx.x;
  int br = x / 24, ck = x % 24;
  int ch = ck / 3, k = ck % 3;
  const float* convW = br ? cvWc : cvWw;
  const float* projW = br ? pjWc : pjWw;
  const float* projb = br ? pjbc : pjbw;
  int d = threadIdx.x;
  float acc = 0.f;
  for (int o = 0; o < 256; o++)
    acc += convW[ch * 768 + o * 3 + k] * projW[o * 256 + d];
  M[(br * 24 + ck) * 256 + d] = acc;
  if (d == 0) {
    float bb = 0.f;
    for (int o = 0; o < 256; o++) bb += convW[ch * 768 + o * 3 + k] * projb[o];
    bK[br * 32 + ck] = bb;
  }
}

// ---------- K3a: folded conv, partial over d-chunks ----------
// grid (split=8, br=2, b=16), 256 threads (l)
__global__ __launch_bounds__(256) void k_conv_a(const float* __restrict__ ph,
                                                const float* __restrict__ M,
                                                float* __restrict__ hpart) {
  int s = blockIdx.x, br = blockIdx.y, b = blockIdx.z;
  int l = threadIdx.x;
  int dbase = s * 32;
  __shared__ float rows[4][258];
  __shared__ float Ml[768];  // [ck=24][dd=32]
  for (int i = l; i < 768; i += 256) {
    int ck = i >> 5, dd = i & 31;
    Ml[i] = M[(br * 24 + ck) * 256 + dbase + dd];
  }
  float acc[8] = {0, 0, 0, 0, 0, 0, 0, 0};
  for (int dd0 = 0; dd0 < 32; dd0 += 4) {
#pragma unroll
    for (int r = 0; r < 4; r++)
      rows[r][1 + l] = ph[((size_t)(b * 256 + dbase + dd0 + r)) * 256 + l];
    if (l < 4) rows[l][0] = 0.f;
    else if (l < 8) rows[l - 4][257] = 0.f;
    __syncthreads();
#pragma unroll
    for (int r = 0; r < 4; r++) {
      float x0 = rows[r][l], x1 = rows[r][l + 1], x2 = rows[r][l + 2];
      int d = dd0 + r;
#pragma unroll
      for (int ch = 0; ch < 8; ch++) {
        acc[ch] += Ml[(ch * 3 + 0) * 32 + d] * x0 +
                   Ml[(ch * 3 + 1) * 32 + d] * x1 +
                   Ml[(ch * 3 + 2) * 32 + d] * x2;
      }
    }
    __syncthreads();
  }
  size_t base = ((size_t)((b * 2 + br) * 256 + l)) * 8;
#pragma unroll
  for (int ch = 0; ch < 8; ch++)
    hpart[(size_t)s * 65536 + base + ch] = acc[ch];
}

// ---------- K3b: sum partials + bias + swish + mask -> hw, hc ----------
// grid (br=2, b=16)
__global__ __launch_bounds__(256) void k_conv_b(const float* __restrict__ hpart,
                                                const float* __restrict__ bK,
                                                const float* __restrict__ cvbw,
                                                const float* __restrict__ cvbc,
                                                const float* __restrict__ dur,
                                                float* __restrict__ hw,
                                                float* __restrict__ hc) {
  int br = blockIdx.x, b = blockIdx.y;
  int l = threadIdx.x;
  const float* convb = br ? cvbc : cvbw;
  const float* bKp = bK + br * 32;
  float dv = dur[b * 256 + l];
  bool vld = (dv != 0.f);
  size_t base = ((size_t)((b * 2 + br) * 256 + l)) * 8;
  float* dst = br ? hc : hw;
#pragma unroll
  for (int ch = 0; ch < 8; ch++) {
    float v = 0.f;
#pragma unroll
    for (int s = 0; s < 8; s++) v += hpart[(size_t)s * 65536 + base + ch];
    v += convb[ch];
    v += bKp[ch * 3 + 1];
    if (l > 0) v += bKp[ch * 3 + 0];
    if (l < 255) v += bKp[ch * 3 + 2];
    v = swishf(v);
    dst[((size_t)(b * 256 + l)) * 8 + ch] = vld ? v : 0.f;
  }
}

// ---------- K4: S/E -> mlp -> softmax -> w (bf16), c, wc ----------
#define TT 8
__global__ __launch_bounds__(256) void k_w(const float* __restrict__ dur,
                                           const float* __restrict__ sk,
                                           const int* __restrict__ frame_len,
                                           const float* __restrict__ hw,
                                           const float* __restrict__ hc,
                                           const float* __restrict__ mlpWw,
                                           const float* __restrict__ mlpbw,
                                           const float* __restrict__ mlpWc,
                                           const float* __restrict__ mlpbc,
                                           unsigned short* __restrict__ wout,
                                           float* __restrict__ wcout) {
  int b = blockIdx.y;
  int t0 = blockIdx.x * TT;
  int l = threadIdx.x;
  int wid = l >> 6, lane = l & 63;
  __shared__ float s_mw[40], s_mbw[4], s_mc[20], s_mbc[2];
  __shared__ float red[4][8];
  if (l < 40) s_mw[l] = mlpWw[l];
  if (l >= 64 && l < 68) s_mbw[l - 64] = mlpbw[l - 64];
  if (l >= 128 && l < 148) s_mc[l - 128] = mlpWc[l - 128];
  if (l >= 192 && l < 194) s_mbc[l - 192] = mlpbc[l - 192];
  float4 a0 = *(const float4*)&hw[((size_t)(b * 256 + l)) * 8];
  float4 a1 = *(const float4*)&hw[((size_t)(b * 256 + l)) * 8 + 4];
  float4 c0 = *(const float4*)&hc[((size_t)(b * 256 + l)) * 8];
  float4 c1 = *(const float4*)&hc[((size_t)(b * 256 + l)) * 8 + 4];
  float hwv[8] = {a0.x, a0.y, a0.z, a0.w, a1.x, a1.y, a1.z, a1.w};
  float hcv[8] = {c0.x, c0.y, c0.z, c0.w, c1.x, c1.y, c1.z, c1.w};
  float dl = dur[b * 256 + l];
  float skl = sk[b * 256 + l];
  int fl = frame_len[b];
  bool valid = (dl != 0.f);
  __syncthreads();
  for (int tt = 0; tt < TT; tt++) {
    int t = t0 + tt;
    size_t wbase = ((size_t)(b * 1000 + t)) * 1024;
    if (t >= fl) {  // frame-padded: w == 0, wc == 0  (block-uniform branch)
#pragma unroll
      for (int q = 0; q < 4; q++) wout[wbase + q * 256 + l] = 0;
      if (l < 8) wcout[((size_t)(b * 1000 + t)) * 8 + l] = 0.f;
      continue;
    }
    float S = valid ? ((float)(t + 1) - skl) : 0.f;
    float E = valid ? dl : 0.f;
    float lg[4];
#pragma unroll
    for (int q = 0; q < 4; q++) {
      float a = s_mbw[q] + S * s_mw[0 * 4 + q] + E * s_mw[1 * 4 + q];
#pragma unroll
      for (int ch = 0; ch < 8; ch++) a += hwv[ch] * s_mw[(2 + ch) * 4 + q];
      lg[q] = valid ? swishf(a) : -INFINITY;
    }
    // block max per q
#pragma unroll
    for (int q = 0; q < 4; q++) {
      float v = lg[q];
#pragma unroll
      for (int m = 1; m < 64; m <<= 1) v = fmaxf(v, __shfl_xor(v, m));
      if (lane == 0) red[wid][q] = v;
    }
    __syncthreads();
    float mx[4];
#pragma unroll
    for (int q = 0; q < 4; q++)
      mx[q] = fmaxf(fmaxf(red[0][q], red[1][q]), fmaxf(red[2][q], red[3][q]));
    __syncthreads();
    float e[4], sm[4];
#pragma unroll
    for (int q = 0; q < 4; q++) {
      e[q] = valid ? expf(lg[q] - mx[q]) : 0.f;
      float v = e[q];
#pragma unroll
      for (int m = 1; m < 64; m <<= 1) v += __shfl_xor(v, m);
      if (lane == 0) red[wid][q] = v;
    }
    __syncthreads();
#pragma unroll
    for (int q = 0; q < 4; q++)
      sm[q] = red[0][q] + red[1][q] + red[2][q] + red[3][q];
    __syncthreads();
    float w4[4];
#pragma unroll
    for (int q = 0; q < 4; q++) {
      w4[q] = e[q] / sm[q];
      wout[wbase + q * 256 + l] = f2bf(w4[q]);
    }
    // c branch (only needed where w != 0; finite everywhere)
    float cp[2];
#pragma unroll
    for (int p = 0; p < 2; p++) {
      float a = s_mbc[p] + S * s_mc[0 * 2 + p] + E * s_mc[1 * 2 + p];
#pragma unroll
      for (int ch = 0; ch < 8; ch++) a += hcv[ch] * s_mc[(2 + ch) * 2 + p];
      cp[p] = swishf(a);
    }
    // wc[q][p] = sum_l w*c
    float pr[8];
#pragma unroll
    for (int q = 0; q < 4; q++)
#pragma unroll
      for (int p = 0; p < 2; p++) pr[q * 2 + p] = w4[q] * cp[p];
#pragma unroll
    for (int j = 0; j < 8; j++) {
      float v = pr[j];
#pragma unroll
      for (int m = 1; m < 64; m <<= 1) v += __shfl_xor(v, m);
      if (lane == 0) red[wid][j] = v;
    }
    __syncthreads();
    if (l == 0) {
#pragma unroll
      for (int j = 0; j < 8; j++)
        wcout[((size_t)(b * 1000 + t)) * 8 + j] =
            red[0][j] + red[1][j] + red[2][j] + red[3][j];
    }
    __syncthreads();
  }
}

// ---------- K5: GEMM1  wh[b][r=t*4+q][h] = sum_l w[b][r][l] * ph[b][h][l] ----------
// grid (63, 4, 16); 64x64 tile, 4x4 microtile, K-chunk 16, K-major LDS (b128 frags)
__global__ __launch_bounds__(256) void k_gemm1(const unsigned short* __restrict__ wmat,
                                               const float* __restrict__ ph,
                                               unsigned short* __restrict__ wh) {
  int b = blockIdx.z;
  int r0 = blockIdx.x * 64, h0 = blockIdx.y * 64;
  int tid = threadIdx.x, tx = tid & 15, ty = tid >> 4;
  __shared__ float As[16][68];
  __shared__ float Bs[16][68];
  float acc[4][4] = {};
  const unsigned short* Ab = wmat + (size_t)b * 4000 * 256;
  const float* Pb = ph + (size_t)b * 65536;
  int arow = tid >> 2, akg = tid & 3;
  int bh = tid & 63, bkg = tid >> 6;
  int gr = r0 + arow;
  for (int k0 = 0; k0 < 256; k0 += 16) {
    float av[4] = {0.f, 0.f, 0.f, 0.f};
    if (gr < 4000) {
      ushort4 u = *(const ushort4*)(Ab + (size_t)gr * 256 + k0 + akg * 4);
      av[0] = bf2f(u.x); av[1] = bf2f(u.y); av[2] = bf2f(u.z); av[3] = bf2f(u.w);
    }
    float4 bv = *(const float4*)(Pb + (size_t)(h0 + bh) * 256 + k0 + bkg * 4);
    __syncthreads();
    As[akg * 4 + 0][arow] = av[0];
    As[akg * 4 + 1][arow] = av[1];
    As[akg * 4 + 2][arow] = av[2];
    As[akg * 4 + 3][arow] = av[3];
    Bs[bkg * 4 + 0][bh] = bv.x;
    Bs[bkg * 4 + 1][bh] = bv.y;
    Bs[bkg * 4 + 2][bh] = bv.z;
    Bs[bkg * 4 + 3][bh] = bv.w;
    __syncthreads();
#pragma unroll
    for (int kk = 0; kk < 16; kk++) {
      float4 a4 = *(const float4*)&As[kk][ty * 4];
      float4 b4 = *(const float4*)&Bs[kk][tx * 4];
      float aa[4] = {a4.x, a4.y, a4.z, a4.w};
      float bb[4] = {b4.x, b4.y, b4.z, b4.w};
#pragma unroll
      for (int i = 0; i < 4; i++)
#pragma unroll
        for (int j = 0; j < 4; j++)
          acc[i][j] = fmaf(aa[i], bb[j], acc[i][j]);
    }
  }
#pragma unroll
  for (int i = 0; i < 4; i++) {
    int rr = r0 + ty * 4 + i;
    if (rr < 4000) {
      ushort4 o;
      o.x = f2bf(acc[i][0]); o.y = f2bf(acc[i][1]);
      o.z = f2bf(acc[i][2]); o.w = f2bf(acc[i][3]);
      *(ushort4*)(wh + ((size_t)b * 4000 + rr) * 256 + h0 + tx * 4) = o;
    }
  }
}

// ---------- K6: GEMM2 + epilogue ----------
// out[m][o] = sum_k wh[m][k]*LW[k][o] + sum_jj wc[m][jj]*LC[jj][o] + lwb[o] + lcb[o]
// grid (250, 4)
__global__ __launch_bounds__(256) void k_gemm2(const unsigned short* __restrict__ wh,
                                               const float* __restrict__ LW,
                                               const float* __restrict__ lwb,
                                               const float* __restrict__ LC,
                                               const float* __restrict__ lcb,
                                               const float* __restrict__ wc,
                                               float* __restrict__ out) {
  int m0 = blockIdx.x * 64, o0 = blockIdx.y * 64;
  int tid = threadIdx.x, tx = tid & 15, ty = tid >> 4;
  __shared__ float As[16][68];
  __shared__ float Bs[16][68];
  __shared__ float s_lc[8][64];
  __shared__ float s_bias[64];
  for (int i = tid; i < 512; i += 256)
    s_lc[i >> 6][i & 63] = LC[(i >> 6) * 256 + o0 + (i & 63)];
  if (tid < 64) s_bias[tid] = lwb[o0 + tid] + lcb[o0 + tid];
  float acc[4][4] = {};
  int arow = tid >> 2, akg = tid & 3;
  int bo = tid & 63, bkg = tid >> 6;
  size_t abase = ((size_t)(m0 + arow)) * 1024 + akg * 4;
  for (int k0 = 0; k0 < 1024; k0 += 16) {
    ushort4 u = *(const ushort4*)(wh + abase + k0);
    float bvv[4];
#pragma unroll
    for (int s = 0; s < 4; s++)
      bvv[s] = LW[(size_t)(k0 + bkg * 4 + s) * 256 + o0 + bo];
    __syncthreads();
    As[akg * 4 + 0][arow] = bf2f(u.x);
    As[akg * 4 + 1][arow] = bf2f(u.y);
    As[akg * 4 + 2][arow] = bf2f(u.z);
    As[akg * 4 + 3][arow] = bf2f(u.w);
    Bs[bkg * 4 + 0][bo] = bvv[0];
    Bs[bkg * 4 + 1][bo] = bvv[1];
    Bs[bkg * 4 + 2][bo] = bvv[2];
    Bs[bkg * 4 + 3][bo] = bvv[3];
    __syncthreads();
#pragma unroll
    for (int kk = 0; kk < 16; kk++) {
      float4 a4 = *(const float4*)&As[kk][ty * 4];
      float4 b4 = *(const float4*)&Bs[kk][tx * 4];
      float aa[4] = {a4.x, a4.y, a4.z, a4.w};
      float bb[4] = {b4.x, b4.y, b4.z, b4.w};
#pragma unroll
      for (int i = 0; i < 4; i++)
#pragma unroll
        for (int j = 0; j < 4; j++)
          acc[i][j] = fmaf(aa[i], bb[j], acc[i][j]);
    }
  }
#pragma unroll
  for (int i = 0; i < 4; i++) {
    int m = m0 + ty * 4 + i;
    const float* wcr = wc + (size_t)m * 8;
    float4 wa = *(const float4*)wcr;
    float4 wb = *(const float4*)(wcr + 4);
    float wcl[8] = {wa.x, wa.y, wa.z, wa.w, wb.x, wb.y, wb.z, wb.w};
    float rr[4];
#pragma unroll
    for (int j = 0; j < 4; j++) {
      int oo = tx * 4 + j;
      float v = acc[i][j] + s_bias[oo];
#pragma unroll
      for (int jj = 0; jj < 8; jj++) v = fmaf(wcl[jj], s_lc[jj][oo], v);
      rr[j] = v;
    }
    float4 r4;
    r4.x = rr[0]; r4.y = rr[1]; r4.z = rr[2]; r4.w = rr[3];
    *(float4*)(out + (size_t)m * 256 + o0 + tx * 4) = r4;
  }
}

// ---------- launch ----------
extern "C" void kernel_launch(void* const* d_in, const int* in_sizes, int n_in,
                              void* d_out, int out_size, void* d_ws, size_t ws_size,
                              hipStream_t stream) {
  const float* dur  = (const float*)d_in[0];
  const float* ph   = (const float*)d_in[1];
  // d_in[2] phoneme_mask (bool) unused: pad derived from durations==0
  const float* pjWw = (const float*)d_in[3];
  const float* pjbw = (const float*)d_in[4];
  const float* cvWw = (const float*)d_in[5];
  const float* cvbw = (const float*)d_in[6];
  const float* mlWw = (const float*)d_in[7];
  const float* mlbw = (const float*)d_in[8];
  const float* liWw = (const float*)d_in[9];
  const float* libw = (const float*)d_in[10];
  const float* pjWc = (const float*)d_in[11];
  const float* pjbc = (const float*)d_in[12];
  const float* cvWc = (const float*)d_in[13];
  const float* cvbc = (const float*)d_in[14];
  const float* mlWc = (const float*)d_in[15];
  const float* mlbc = (const float*)d_in[16];
  const float* liWc = (const float*)d_in[17];
  const float* libc = (const float*)d_in[18];
  float* out = (float*)d_out;

  float* f = (float*)d_ws;
  size_t o = 0;
  float* sk = f + o;            o += 4096;
  int* fl = (int*)(f + o);      o += 16;
  float* M = f + o;             o += 2 * 24 * 256;      // 12288
  float* bK = f + o;            o += 64;
  float* hpart = f + o;         o += 8 * 16 * 2 * 256 * 8;  // 524288
  float* hw = f + o;            o += 16 * 256 * 8;      // 32768
  float* hc = f + o;            o += 16 * 256 * 8;      // 32768
  float* wc = f + o;            o += 16 * 1000 * 8;     // 128000
  unsigned short* wmat = (unsigned short*)(f + o); o += 8192000;  // 16.384M bf16
  unsigned short* wh   = (unsigned short*)(f + o); o += 8192000;  // 16.384M bf16
  // total ~68.5 MB of d_ws

  k_scan<<<16, 256, 0, stream>>>(dur, sk, fl);
  k_fold<<<48, 256, 0, stream>>>(cvWw, pjWw, pjbw, cvWc, pjWc, pjbc, M, bK);
  k_conv_a<<<dim3(8, 2, 16), 256, 0, stream>>>(ph, M, hpart);
  k_conv_b<<<dim3(2, 16), 256, 0, stream>>>(hpart, bK, cvbw, cvbc, dur, hw, hc);
  k_w<<<dim3(125, 16), 256, 0, stream>>>(dur, sk, fl, hw, hc, mlWw, mlbw, mlWc,
                                         mlbc, wmat, wc);
  k_gemm1<<<dim3(63, 4, 16), 256, 0, stream>>>(wmat, ph, wh);
  k_gemm2<<<dim3(250, 4), 256, 0, stream>>>(wh, liWw, libw, liWc, libc, wc, out);
}

// Round 2
// 220.978 us; speedup vs baseline: 2.1719x; 2.1719x over previous
//
#include <hip/hip_runtime.h>

// B=16, D=256, L=256, T=1000, K=3, DW=4, DC=2, CH=8

typedef short v8s __attribute__((ext_vector_type(8)));
typedef float f4 __attribute__((ext_vector_type(4)));

__device__ __forceinline__ float bf2f(unsigned short h) {
  return __uint_as_float(((unsigned int)h) << 16);
}
__device__ __forceinline__ unsigned short f2bf(float f) {
  unsigned int u = __float_as_uint(f);
  u = (u + 0x7FFFu + ((u >> 16) & 1u)) >> 16;
  return (unsigned short)u;
}
__device__ __forceinline__ float swishf(float x) {
  return x * __builtin_amdgcn_rcpf(1.f + __expf(-x));
}

// ---------- K1: inclusive scan of durations -> sk, frame_len ----------
__global__ __launch_bounds__(256) void k_scan(const float* __restrict__ dur,
                                              float* __restrict__ sk,
                                              int* __restrict__ frame_len) {
  int b = blockIdx.x, l = threadIdx.x;
  __shared__ float s[256];
  float d = dur[b * 256 + l];
  s[l] = d;
  __syncthreads();
  for (int off = 1; off < 256; off <<= 1) {
    float v = (l >= off) ? s[l - off] : 0.f;
    __syncthreads();
    s[l] += v;
    __syncthreads();
  }
  sk[b * 256 + l] = s[l] - d;
  if (l == 255) {
    int fl = (int)rintf(s[255]);
    fl = min(max(fl, 0), 1000);
    frame_len[b] = fl;
  }
}

// ---------- K2: fold proj into conv ----------
__global__ __launch_bounds__(256) void k_fold(const float* __restrict__ cvWw,
                                              const float* __restrict__ pjWw,
                                              const float* __restrict__ pjbw,
                                              const float* __restrict__ cvWc,
                                              const float* __restrict__ pjWc,
                                              const float* __restrict__ pjbc,
                                              float* __restrict__ M,
                                              float* __restrict__ bK) {
  int x = blockIdx.x;
  int br = x / 24, ck = x % 24;
  int ch = ck / 3, k = ck % 3;
  const float* convW = br ? cvWc : cvWw;
  const float* projW = br ? pjWc : pjWw;
  const float* projb = br ? pjbc : pjbw;
  int d = threadIdx.x;
  float acc = 0.f;
  for (int o = 0; o < 256; o++)
    acc += convW[ch * 768 + o * 3 + k] * projW[o * 256 + d];
  M[(br * 24 + ck) * 256 + d] = acc;
  if (d == 0) {
    float bb = 0.f;
    for (int o = 0; o < 256; o++) bb += convW[ch * 768 + o * 3 + k] * projb[o];
    bK[br * 32 + ck] = bb;
  }
}

// ---------- K3a: folded conv, partial over d-chunks ----------
__global__ __launch_bounds__(256) void k_conv_a(const float* __restrict__ ph,
                                                const float* __restrict__ M,
                                                float* __restrict__ hpart) {
  int s = blockIdx.x, br = blockIdx.y, b = blockIdx.z;
  int l = threadIdx.x;
  int dbase = s * 32;
  __shared__ float rows[4][258];
  __shared__ float Ml[768];
  for (int i = l; i < 768; i += 256) {
    int ck = i >> 5, dd = i & 31;
    Ml[i] = M[(br * 24 + ck) * 256 + dbase + dd];
  }
  float acc[8] = {0, 0, 0, 0, 0, 0, 0, 0};
  for (int dd0 = 0; dd0 < 32; dd0 += 4) {
#pragma unroll
    for (int r = 0; r < 4; r++)
      rows[r][1 + l] = ph[((size_t)(b * 256 + dbase + dd0 + r)) * 256 + l];
    if (l < 4) rows[l][0] = 0.f;
    else if (l < 8) rows[l - 4][257] = 0.f;
    __syncthreads();
#pragma unroll
    for (int r = 0; r < 4; r++) {
      float x0 = rows[r][l], x1 = rows[r][l + 1], x2 = rows[r][l + 2];
      int d = dd0 + r;
#pragma unroll
      for (int ch = 0; ch < 8; ch++) {
        acc[ch] += Ml[(ch * 3 + 0) * 32 + d] * x0 +
                   Ml[(ch * 3 + 1) * 32 + d] * x1 +
                   Ml[(ch * 3 + 2) * 32 + d] * x2;
      }
    }
    __syncthreads();
  }
  size_t base = ((size_t)((b * 2 + br) * 256 + l)) * 8;
#pragma unroll
  for (int ch = 0; ch < 8; ch++)
    hpart[(size_t)s * 65536 + base + ch] = acc[ch];
}

// ---------- K3b: sum partials + bias + swish + mask ----------
__global__ __launch_bounds__(256) void k_conv_b(const float* __restrict__ hpart,
                                                const float* __restrict__ bK,
                                                const float* __restrict__ cvbw,
                                                const float* __restrict__ cvbc,
                                                const float* __restrict__ dur,
                                                float* __restrict__ hw,
                                                float* __restrict__ hc) {
  int br = blockIdx.x, b = blockIdx.y;
  int l = threadIdx.x;
  const float* convb = br ? cvbc : cvbw;
  const float* bKp = bK + br * 32;
  float dv = dur[b * 256 + l];
  bool vld = (dv != 0.f);
  size_t base = ((size_t)((b * 2 + br) * 256 + l)) * 8;
  float* dst = br ? hc : hw;
#pragma unroll
  for (int ch = 0; ch < 8; ch++) {
    float v = 0.f;
#pragma unroll
    for (int s = 0; s < 8; s++) v += hpart[(size_t)s * 65536 + base + ch];
    v += convb[ch];
    v += bKp[ch * 3 + 1];
    if (l > 0) v += bKp[ch * 3 + 0];
    if (l < 255) v += bKp[ch * 3 + 2];
    v = swishf(v);
    dst[((size_t)(b * 256 + l)) * 8 + ch] = vld ? v : 0.f;
  }
}

// ---------- transpose LW[1024][256] f32 -> LWT[256][1024] bf16 ----------
__global__ __launch_bounds__(256) void k_tr_lw(const float* __restrict__ src,
                                               unsigned short* __restrict__ dst) {
  int kt = blockIdx.x, ot = blockIdx.y;
  int tx = threadIdx.x & 31, ty = threadIdx.x >> 5;
  __shared__ float tile[32][33];
#pragma unroll
  for (int r = 0; r < 4; r++) {
    int row = ty + r * 8;
    tile[row][tx] = src[(size_t)(kt * 32 + row) * 256 + ot * 32 + tx];
  }
  __syncthreads();
#pragma unroll
  for (int r = 0; r < 4; r++) {
    int row = ty + r * 8;
    dst[(size_t)(ot * 32 + row) * 1024 + kt * 32 + tx] = f2bf(tile[tx][row]);
  }
}

// ---------- transpose ph[b][256][256] f32 -> phT[b][l][h] bf16 ----------
__global__ __launch_bounds__(256) void k_tr_ph(const float* __restrict__ src,
                                               unsigned short* __restrict__ dst) {
  int ht = blockIdx.x, lt = blockIdx.y, b = blockIdx.z;
  int tx = threadIdx.x & 31, ty = threadIdx.x >> 5;
  __shared__ float tile[32][33];
#pragma unroll
  for (int r = 0; r < 4; r++) {
    int row = ty + r * 8;
    tile[row][tx] =
        src[(size_t)b * 65536 + (size_t)(ht * 32 + row) * 256 + lt * 32 + tx];
  }
  __syncthreads();
#pragma unroll
  for (int r = 0; r < 4; r++) {
    int row = ty + r * 8;
    dst[(size_t)b * 65536 + (size_t)(lt * 32 + row) * 256 + ht * 32 + tx] =
        f2bf(tile[tx][row]);
  }
}

// ---------- K4: wave-per-t softmax -> w (bf16 [b][t][q][l]), wc ----------
__global__ __launch_bounds__(256) void k_w(const float* __restrict__ dur,
                                           const float* __restrict__ sk,
                                           const int* __restrict__ frame_len,
                                           const float* __restrict__ hw,
                                           const float* __restrict__ hc,
                                           const float* __restrict__ mlpWw,
                                           const float* __restrict__ mlpbw,
                                           const float* __restrict__ mlpWc,
                                           const float* __restrict__ mlpbc,
                                           unsigned short* __restrict__ wout,
                                           float* __restrict__ wcout) {
  int b = blockIdx.y;
  int tid = threadIdx.x;
  int wave = tid >> 6, lane = tid & 63;
  int tbase = blockIdx.x * 32 + wave * 8;
  int l0 = lane * 4;

  float mw[40], mbw[4], mc[20], mbc[2];
#pragma unroll
  for (int i = 0; i < 40; i++) mw[i] = mlpWw[i];
#pragma unroll
  for (int i = 0; i < 4; i++) mbw[i] = mlpbw[i];
#pragma unroll
  for (int i = 0; i < 20; i++) mc[i] = mlpWc[i];
#pragma unroll
  for (int i = 0; i < 2; i++) mbc[i] = mlpbc[i];

  float4 dv4 = *(const float4*)&dur[b * 256 + l0];
  float4 sk4 = *(const float4*)&sk[b * 256 + l0];
  float dv[4] = {dv4.x, dv4.y, dv4.z, dv4.w};
  float skv[4] = {sk4.x, sk4.y, sk4.z, sk4.w};
  bool val[4];
#pragma unroll
  for (int j = 0; j < 4; j++) val[j] = (dv[j] != 0.f);

  float hwv[4][8], hcv[4][8];
#pragma unroll
  for (int j = 0; j < 4; j++) {
    float4 a0 = *(const float4*)&hw[((size_t)(b * 256 + l0 + j)) * 8];
    float4 a1 = *(const float4*)&hw[((size_t)(b * 256 + l0 + j)) * 8 + 4];
    float4 c0 = *(const float4*)&hc[((size_t)(b * 256 + l0 + j)) * 8];
    float4 c1 = *(const float4*)&hc[((size_t)(b * 256 + l0 + j)) * 8 + 4];
    hwv[j][0] = a0.x; hwv[j][1] = a0.y; hwv[j][2] = a0.z; hwv[j][3] = a0.w;
    hwv[j][4] = a1.x; hwv[j][5] = a1.y; hwv[j][6] = a1.z; hwv[j][7] = a1.w;
    hcv[j][0] = c0.x; hcv[j][1] = c0.y; hcv[j][2] = c0.z; hcv[j][3] = c0.w;
    hcv[j][4] = c1.x; hcv[j][5] = c1.y; hcv[j][6] = c1.z; hcv[j][7] = c1.w;
  }

  // t-independent logit bases
  float basew[4][4], basec[4][2];
#pragma unroll
  for (int j = 0; j < 4; j++) {
#pragma unroll
    for (int q = 0; q < 4; q++) {
      float a = mbw[q] + dv[j] * mw[4 + q];
#pragma unroll
      for (int ch = 0; ch < 8; ch++) a += hwv[j][ch] * mw[(2 + ch) * 4 + q];
      basew[j][q] = a;
    }
#pragma unroll
    for (int p = 0; p < 2; p++) {
      float a = mbc[p] + dv[j] * mc[2 + p];
#pragma unroll
      for (int ch = 0; ch < 8; ch++) a += hcv[j][ch] * mc[(2 + ch) * 2 + p];
      basec[j][p] = a;
    }
  }

  int fl = frame_len[b];
  for (int i = 0; i < 8; i++) {
    int t = tbase + i;
    if (t >= 1000) break;
    size_t wbase = ((size_t)(b * 1000 + t)) * 1024;
    if (t >= fl) {
      ushort4 z = {0, 0, 0, 0};
#pragma unroll
      for (int q = 0; q < 4; q++) *(ushort4*)(wout + wbase + q * 256 + l0) = z;
      if (lane == 0) {
        float4 fz = {0.f, 0.f, 0.f, 0.f};
        *(float4*)(wcout + ((size_t)(b * 1000 + t)) * 8) = fz;
        *(float4*)(wcout + ((size_t)(b * 1000 + t)) * 8 + 4) = fz;
      }
      continue;
    }
    float S[4];
#pragma unroll
    for (int j = 0; j < 4; j++) S[j] = (float)(t + 1) - skv[j];
    float lg[4][4];
#pragma unroll
    for (int j = 0; j < 4; j++)
#pragma unroll
      for (int q = 0; q < 4; q++)
        lg[j][q] = val[j] ? swishf(basew[j][q] + S[j] * mw[q]) : -INFINITY;
    // max over l
    float mx[4];
#pragma unroll
    for (int q = 0; q < 4; q++) {
      float v = fmaxf(fmaxf(lg[0][q], lg[1][q]), fmaxf(lg[2][q], lg[3][q]));
#pragma unroll
      for (int m = 1; m < 64; m <<= 1) v = fmaxf(v, __shfl_xor(v, m));
      mx[q] = v;
    }
    float e[4][4];
#pragma unroll
    for (int j = 0; j < 4; j++)
#pragma unroll
      for (int q = 0; q < 4; q++)
        e[j][q] = val[j] ? __expf(lg[j][q] - mx[q]) : 0.f;
    float inv[4];
#pragma unroll
    for (int q = 0; q < 4; q++) {
      float v = (e[0][q] + e[1][q]) + (e[2][q] + e[3][q]);
#pragma unroll
      for (int m = 1; m < 64; m <<= 1) v += __shfl_xor(v, m);
      inv[q] = __builtin_amdgcn_rcpf(v);
    }
    float w[4][4];
#pragma unroll
    for (int q = 0; q < 4; q++) {
      ushort4 o4;
      w[0][q] = e[0][q] * inv[q]; w[1][q] = e[1][q] * inv[q];
      w[2][q] = e[2][q] * inv[q]; w[3][q] = e[3][q] * inv[q];
      o4.x = f2bf(w[0][q]); o4.y = f2bf(w[1][q]);
      o4.z = f2bf(w[2][q]); o4.w = f2bf(w[3][q]);
      *(ushort4*)(wout + wbase + q * 256 + l0) = o4;
    }
    // c branch + wc reduction
    float cp[4][2];
#pragma unroll
    for (int j = 0; j < 4; j++)
#pragma unroll
      for (int p = 0; p < 2; p++)
        cp[j][p] = swishf(basec[j][p] + S[j] * mc[p]);
    float pr[8];
#pragma unroll
    for (int q = 0; q < 4; q++)
#pragma unroll
      for (int p = 0; p < 2; p++) {
        float v = w[0][q] * cp[0][p] + w[1][q] * cp[1][p] +
                  w[2][q] * cp[2][p] + w[3][q] * cp[3][p];
#pragma unroll
        for (int m = 1; m < 64; m <<= 1) v += __shfl_xor(v, m);
        pr[q * 2 + p] = v;
      }
    if (lane == 0) {
      float4 lo = {pr[0], pr[1], pr[2], pr[3]};
      float4 hi = {pr[4], pr[5], pr[6], pr[7]};
      *(float4*)(wcout + ((size_t)(b * 1000 + t)) * 8) = lo;
      *(float4*)(wcout + ((size_t)(b * 1000 + t)) * 8 + 4) = hi;
    }
  }
}

// ---------- K5: gemmG  G[b][o][q*256+l] = sum_h LWT[o][q*256+h]*phT[b][l][h] ----------
// BM=64 (o), BN=128 (l), BK=32, K=256. grid (8, 4, 16)
__global__ __launch_bounds__(256) void k_gemmG(const unsigned short* __restrict__ LWT,
                                               const unsigned short* __restrict__ phT,
                                               unsigned short* __restrict__ G) {
  int q = blockIdx.y, b = blockIdx.z;
  int o0 = (blockIdx.x >> 1) * 64;
  int l0 = (blockIdx.x & 1) * 128;
  int tid = threadIdx.x, wave = tid >> 6, lane = tid & 63;
  int quad = lane >> 4, col = lane & 15;
  __shared__ __align__(16) unsigned short Asm[64 * 40];
  __shared__ __align__(16) unsigned short Bsm[128 * 40];

  int arow = wave * 16 + (lane >> 2);
  int aseg = lane & 3;
  const unsigned short* Ag = LWT + (size_t)(o0 + arow) * 1024 + q * 256 + aseg * 8;
  unsigned short* Al = Asm + arow * 40 + aseg * 8;
  int brow = wave * 32 + (lane >> 2);
  const unsigned short* Bg0 = phT + (size_t)b * 65536 + (size_t)(l0 + brow) * 256 + aseg * 8;
  const unsigned short* Bg1 = Bg0 + 16 * 256;
  unsigned short* Bl0 = Bsm + brow * 40 + aseg * 8;
  unsigned short* Bl1 = Bl0 + 16 * 40;

  int wm = (wave & 1) * 32, wn = (wave >> 1) * 64;
  f4 acc[2][4];
#pragma unroll
  for (int i = 0; i < 2; i++)
#pragma unroll
    for (int j = 0; j < 4; j++) acc[i][j] = (f4){0.f, 0.f, 0.f, 0.f};

  uint4 ra = *(const uint4*)Ag;
  uint4 rb0 = *(const uint4*)Bg0;
  uint4 rb1 = *(const uint4*)Bg1;
  for (int k0 = 0; k0 < 256; k0 += 32) {
    __syncthreads();
    *(uint4*)Al = ra;
    *(uint4*)Bl0 = rb0;
    *(uint4*)Bl1 = rb1;
    __syncthreads();
    if (k0 + 32 < 256) {
      ra = *(const uint4*)(Ag + k0 + 32);
      rb0 = *(const uint4*)(Bg0 + k0 + 32);
      rb1 = *(const uint4*)(Bg1 + k0 + 32);
    }
    v8s af[2], bf[4];
#pragma unroll
    for (int mt = 0; mt < 2; mt++)
      af[mt] = *(const v8s*)(Asm + (wm + mt * 16 + col) * 40 + quad * 8);
#pragma unroll
    for (int nt = 0; nt < 4; nt++)
      bf[nt] = *(const v8s*)(Bsm + (wn + nt * 16 + col) * 40 + quad * 8);
#pragma unroll
    for (int mt = 0; mt < 2; mt++)
#pragma unroll
      for (int nt = 0; nt < 4; nt++)
        acc[mt][nt] = __builtin_amdgcn_mfma_f32_16x16x32_bf16(af[mt], bf[nt],
                                                              acc[mt][nt], 0, 0, 0);
  }
#pragma unroll
  for (int mt = 0; mt < 2; mt++)
#pragma unroll
    for (int nt = 0; nt < 4; nt++)
#pragma unroll
      for (int r = 0; r < 4; r++) {
        int orow = o0 + wm + mt * 16 + quad * 4 + r;
        int lcol = l0 + wn + nt * 16 + col;
        G[(size_t)b * 262144 + (size_t)orow * 1024 + q * 256 + lcol] =
            f2bf(acc[mt][nt][r]);
      }
}

// ---------- K6: gemmF  out[b][t][o] = sum_kk w[b][t][kk]*G[b][o][kk] + epilogue ----------
// BM=64 (t), BN=128 (o), BK=32, K=1024. grid (32, 16)
__global__ __launch_bounds__(256) void k_gemmF(const unsigned short* __restrict__ wbuf,
                                               const unsigned short* __restrict__ G,
                                               const float* __restrict__ lwb,
                                               const float* __restrict__ lcb,
                                               const float* __restrict__ LC,
                                               const float* __restrict__ wc,
                                               float* __restrict__ out) {
  int b = blockIdx.y;
  int t0 = (blockIdx.x >> 1) * 64;
  int o0 = (blockIdx.x & 1) * 128;
  int tid = threadIdx.x, wave = tid >> 6, lane = tid & 63;
  int quad = lane >> 4, col = lane & 15;
  __shared__ __align__(16) unsigned short Asm[64 * 40];
  __shared__ __align__(16) unsigned short Bsm[128 * 40];
  __shared__ float bias_s[128];
  __shared__ float lcs[8][128];
  __shared__ float wcs[64][8];

  for (int i = tid; i < 128; i += 256) bias_s[i] = lwb[o0 + i] + lcb[o0 + i];
  for (int i = tid; i < 1024; i += 256)
    lcs[i >> 7][i & 127] = LC[(i >> 7) * 256 + o0 + (i & 127)];
  for (int i = tid; i < 512; i += 256) {
    int r = i >> 3, j = i & 7;
    int t = t0 + r;
    wcs[r][j] = (t < 1000) ? wc[((size_t)(b * 1000 + t)) * 8 + j] : 0.f;
  }

  int arow = wave * 16 + (lane >> 2);
  int aseg = lane & 3;
  const unsigned short* Ag =
      wbuf + (size_t)b * 1024000 + (size_t)(t0 + arow) * 1024 + aseg * 8;
  unsigned short* Al = Asm + arow * 40 + aseg * 8;
  int brow = wave * 32 + (lane >> 2);
  const unsigned short* Bg0 =
      G + (size_t)b * 262144 + (size_t)(o0 + brow) * 1024 + aseg * 8;
  const unsigned short* Bg1 = Bg0 + 16 * 1024;
  unsigned short* Bl0 = Bsm + brow * 40 + aseg * 8;
  unsigned short* Bl1 = Bl0 + 16 * 40;

  int wm = (wave & 1) * 32, wn = (wave >> 1) * 64;
  f4 acc[2][4];
#pragma unroll
  for (int i = 0; i < 2; i++)
#pragma unroll
    for (int j = 0; j < 4; j++) acc[i][j] = (f4){0.f, 0.f, 0.f, 0.f};

  uint4 ra = *(const uint4*)Ag;
  uint4 rb0 = *(const uint4*)Bg0;
  uint4 rb1 = *(const uint4*)Bg1;
  for (int k0 = 0; k0 < 1024; k0 += 32) {
    __syncthreads();
    *(uint4*)Al = ra;
    *(uint4*)Bl0 = rb0;
    *(uint4*)Bl1 = rb1;
    __syncthreads();
    if (k0 + 32 < 1024) {
      ra = *(const uint4*)(Ag + k0 + 32);
      rb0 = *(const uint4*)(Bg0 + k0 + 32);
      rb1 = *(const uint4*)(Bg1 + k0 + 32);
    }
    v8s af[2], bf[4];
#pragma unroll
    for (int mt = 0; mt < 2; mt++)
      af[mt] = *(const v8s*)(Asm + (wm + mt * 16 + col) * 40 + quad * 8);
#pragma unroll
    for (int nt = 0; nt < 4; nt++)
      bf[nt] = *(const v8s*)(Bsm + (wn + nt * 16 + col) * 40 + quad * 8);
#pragma unroll
    for (int mt = 0; mt < 2; mt++)
#pragma unroll
      for (int nt = 0; nt < 4; nt++)
        acc[mt][nt] = __builtin_amdgcn_mfma_f32_16x16x32_bf16(af[mt], bf[nt],
                                                              acc[mt][nt], 0, 0, 0);
  }
#pragma unroll
  for (int mt = 0; mt < 2; mt++)
#pragma unroll
    for (int r = 0; r < 4; r++) {
      int lrow = wm + mt * 16 + quad * 4 + r;
      int trow = t0 + lrow;
      if (trow < 1000) {
        float wcl[8];
        float4 wa = *(const float4*)&wcs[lrow][0];
        float4 wb = *(const float4*)&wcs[lrow][4];
        wcl[0] = wa.x; wcl[1] = wa.y; wcl[2] = wa.z; wcl[3] = wa.w;
        wcl[4] = wb.x; wcl[5] = wb.y; wcl[6] = wb.z; wcl[7] = wb.w;
#pragma unroll
        for (int nt = 0; nt < 4; nt++) {
          int oc = wn + nt * 16 + col;
          float v = acc[mt][nt][r] + bias_s[oc];
#pragma unroll
          for (int jj = 0; jj < 8; jj++) v = fmaf(wcl[jj], lcs[jj][oc], v);
          out[((size_t)(b * 1000 + trow)) * 256 + o0 + oc] = v;
        }
      }
    }
}

// ---------- launch ----------
extern "C" void kernel_launch(void* const* d_in, const int* in_sizes, int n_in,
                              void* d_out, int out_size, void* d_ws, size_t ws_size,
                              hipStream_t stream) {
  const float* dur  = (const float*)d_in[0];
  const float* ph   = (const float*)d_in[1];
  const float* pjWw = (const float*)d_in[3];
  const float* pjbw = (const float*)d_in[4];
  const float* cvWw = (const float*)d_in[5];
  const float* cvbw = (const float*)d_in[6];
  const float* mlWw = (const float*)d_in[7];
  const float* mlbw = (const float*)d_in[8];
  const float* liWw = (const float*)d_in[9];
  const float* libw = (const float*)d_in[10];
  const float* pjWc = (const float*)d_in[11];
  const float* pjbc = (const float*)d_in[12];
  const float* cvWc = (const float*)d_in[13];
  const float* cvbc = (const float*)d_in[14];
  const float* mlWc = (const float*)d_in[15];
  const float* mlbc = (const float*)d_in[16];
  const float* liWc = (const float*)d_in[17];
  const float* libc = (const float*)d_in[18];
  float* out = (float*)d_out;

  float* f = (float*)d_ws;
  size_t o = 0;
  float* sk = f + o;            o += 4096;
  int* fl = (int*)(f + o);      o += 16;
  float* M = f + o;             o += 2 * 24 * 256;
  float* bK = f + o;            o += 64;
  float* hpart = f + o;         o += 8 * 16 * 2 * 256 * 8;   // 524288
  float* hw = f + o;            o += 16 * 256 * 8;
  float* hc = f + o;            o += 16 * 256 * 8;
  float* wc = f + o;            o += 16 * 1000 * 8;
  unsigned short* wbuf = (unsigned short*)(f + o); o += 8224768;  // 16.384M + 64K slack (bf16)
  unsigned short* G    = (unsigned short*)(f + o); o += 2097152;  // 4.19M bf16
  unsigned short* phT  = (unsigned short*)(f + o); o += 524288;   // 1.05M bf16
  unsigned short* LWT  = (unsigned short*)(f + o); o += 131072;   // 262K bf16
  // ~47 MB total

  k_scan<<<16, 256, 0, stream>>>(dur, sk, fl);
  k_fold<<<48, 256, 0, stream>>>(cvWw, pjWw, pjbw, cvWc, pjWc, pjbc, M, bK);
  k_tr_lw<<<dim3(32, 8), 256, 0, stream>>>(liWw, LWT);
  k_tr_ph<<<dim3(8, 8, 16), 256, 0, stream>>>(ph, phT);
  k_conv_a<<<dim3(8, 2, 16), 256, 0, stream>>>(ph, M, hpart);
  k_conv_b<<<dim3(2, 16), 256, 0, stream>>>(hpart, bK, cvbw, cvbc, dur, hw, hc);
  k_w<<<dim3(32, 16), 256, 0, stream>>>(dur, sk, fl, hw, hc, mlWw, mlbw, mlWc,
                                        mlbc, wbuf, wc);
  k_gemmG<<<dim3(8, 4, 16), 256, 0, stream>>>(LWT, phT, G);
  k_gemmF<<<dim3(32, 16), 256, 0, stream>>>(wbuf, G, libw, libc, liWc, wc, out);
}

// Round 3
// 187.887 us; speedup vs baseline: 2.5545x; 1.1761x over previous
//
#include <hip/hip_runtime.h>

// B=16, D=256, L=256, T=1000, K=3, DW=4, DC=2, CH=8

typedef short v8s __attribute__((ext_vector_type(8)));
typedef float f4 __attribute__((ext_vector_type(4)));

__device__ __forceinline__ float bf2f(unsigned short h) {
  return __uint_as_float(((unsigned int)h) << 16);
}
__device__ __forceinline__ unsigned short f2bf(float f) {
  unsigned int u = __float_as_uint(f);
  u = (u + 0x7FFFu + ((u >> 16) & 1u)) >> 16;
  return (unsigned short)u;
}
__device__ __forceinline__ float swishf(float x) {
  return x * __builtin_amdgcn_rcpf(1.f + __expf(-x));
}

// =======================================================================
// K_PREP: level-0 work, branch on blockIdx.x
//   blk [0,16)    : scan of durations (b = blk) -> sk, frame_len
//   blk [16,64)   : fold proj into conv -> Mb (bf16 [48][256]), bK[48]
//   blk [64,320)  : transpose LW[1024][256] f32 -> LWT[256][1024] bf16
//   blk [320,1344): transpose ph[b][256][256] f32 -> phT[b][l][h] bf16
// =======================================================================
__global__ __launch_bounds__(256) void k_prep(
    const float* __restrict__ dur, const float* __restrict__ ph,
    const float* __restrict__ liWw,
    const float* __restrict__ cvWw, const float* __restrict__ pjWw,
    const float* __restrict__ pjbw,
    const float* __restrict__ cvWc, const float* __restrict__ pjWc,
    const float* __restrict__ pjbc,
    float* __restrict__ sk, int* __restrict__ frame_len,
    unsigned short* __restrict__ Mb, float* __restrict__ bK,
    unsigned short* __restrict__ LWT, unsigned short* __restrict__ phT) {
  __shared__ float sm[32 * 33];
  int blk = blockIdx.x, tid = threadIdx.x;
  if (blk < 16) {
    int b = blk, l = tid;
    float d = dur[b * 256 + l];
    sm[l] = d;
    __syncthreads();
    for (int off = 1; off < 256; off <<= 1) {
      float v = (l >= off) ? sm[l - off] : 0.f;
      __syncthreads();
      sm[l] += v;
      __syncthreads();
    }
    sk[b * 256 + l] = sm[l] - d;
    if (l == 255) {
      int fl = (int)rintf(sm[255]);
      frame_len[b] = min(max(fl, 0), 1000);
    }
  } else if (blk < 64) {
    int x = blk - 16;
    int br = x / 24, ck = x % 24;
    int ch = ck / 3, k = ck % 3;
    const float* convW = br ? cvWc : cvWw;
    const float* projW = br ? pjWc : pjWw;
    const float* projb = br ? pjbc : pjbw;
    int d = tid;
    float acc = 0.f;
    for (int o = 0; o < 256; o++)
      acc += convW[ch * 768 + o * 3 + k] * projW[o * 256 + d];
    Mb[(br * 24 + ck) * 256 + d] = f2bf(acc);
    if (d == 0) {
      float bb = 0.f;
      for (int o = 0; o < 256; o++)
        bb += convW[ch * 768 + o * 3 + k] * projb[o];
      bK[br * 24 + ck] = bb;
    }
  } else if (blk < 320) {
    int idx = blk - 64;
    int kt = idx & 31, ot = idx >> 5;
    int tx = tid & 31, ty = tid >> 5;
#pragma unroll
    for (int r = 0; r < 4; r++) {
      int row = ty + r * 8;
      sm[row * 33 + tx] = liWw[(size_t)(kt * 32 + row) * 256 + ot * 32 + tx];
    }
    __syncthreads();
#pragma unroll
    for (int r = 0; r < 4; r++) {
      int row = ty + r * 8;
      LWT[(size_t)(ot * 32 + row) * 1024 + kt * 32 + tx] =
          f2bf(sm[tx * 33 + row]);
    }
  } else {
    int idx = blk - 320;
    int ht = idx & 7, lt = (idx >> 3) & 7, b = idx >> 6;
    int tx = tid & 31, ty = tid >> 5;
#pragma unroll
    for (int r = 0; r < 4; r++) {
      int row = ty + r * 8;
      sm[row * 33 + tx] =
          ph[(size_t)b * 65536 + (size_t)(ht * 32 + row) * 256 + lt * 32 + tx];
    }
    __syncthreads();
#pragma unroll
    for (int r = 0; r < 4; r++) {
      int row = ty + r * 8;
      phT[(size_t)b * 65536 + (size_t)(lt * 32 + row) * 256 + ht * 32 + tx] =
          f2bf(sm[tx * 33 + row]);
    }
  }
}

// =======================================================================
// K_CONV: per-b MFMA conv. C[l][ck] = sum_d phT[b][l][d]*Mb[ck][d], then
// 3-tap combine + folded biases + swish + mask -> hw, hc. grid 16.
// =======================================================================
__global__ __launch_bounds__(256) void k_conv(
    const unsigned short* __restrict__ phT, const unsigned short* __restrict__ Mb,
    const float* __restrict__ bK, const float* __restrict__ cvbw,
    const float* __restrict__ cvbc, const float* __restrict__ dur,
    float* __restrict__ hw, float* __restrict__ hc) {
  __shared__ float C[256 * 49];  // 50.2 KB
  int b = blockIdx.x;
  int tid = threadIdx.x, wave = tid >> 6, lane = tid & 63;
  int quad = lane >> 4, col = lane & 15;
  int l0 = wave * 64;
  const unsigned short* Ab = phT + (size_t)b * 65536;
  f4 acc[4][3] = {};
#pragma unroll
  for (int k0 = 0; k0 < 256; k0 += 32) {
    v8s af[4], bf[3];
#pragma unroll
    for (int lt = 0; lt < 4; lt++)
      af[lt] = *(const v8s*)(Ab + (size_t)(l0 + lt * 16 + col) * 256 + k0 + quad * 8);
#pragma unroll
    for (int ct = 0; ct < 3; ct++)
      bf[ct] = *(const v8s*)(Mb + (size_t)(ct * 16 + col) * 256 + k0 + quad * 8);
#pragma unroll
    for (int lt = 0; lt < 4; lt++)
#pragma unroll
      for (int ct = 0; ct < 3; ct++)
        acc[lt][ct] = __builtin_amdgcn_mfma_f32_16x16x32_bf16(af[lt], bf[ct],
                                                              acc[lt][ct], 0, 0, 0);
  }
#pragma unroll
  for (int lt = 0; lt < 4; lt++)
#pragma unroll
    for (int ct = 0; ct < 3; ct++)
#pragma unroll
      for (int r = 0; r < 4; r++)
        C[(l0 + lt * 16 + quad * 4 + r) * 49 + ct * 16 + col] = acc[lt][ct][r];
  __syncthreads();
  int l = tid;
  float dv = dur[b * 256 + l];
  bool vld = (dv != 0.f);
#pragma unroll
  for (int br = 0; br < 2; br++) {
    const float* convb = br ? cvbc : cvbw;
    float* dst = br ? hc : hw;
#pragma unroll
    for (int ch = 0; ch < 8; ch++) {
      int ck = br * 24 + ch * 3;
      float v = convb[ch] + bK[ck + 1] + C[l * 49 + ck + 1];
      if (l > 0) v += bK[ck + 0] + C[(l - 1) * 49 + ck + 0];
      if (l < 255) v += bK[ck + 2] + C[(l + 1) * 49 + ck + 2];
      v = swishf(v);
      dst[((size_t)(b * 256 + l)) * 8 + ch] = vld ? v : 0.f;
    }
  }
}

// =======================================================================
// K_WG: blk [0,512) = gemmG  G[b][o][q*256+l] = sum_h LWT[o][q*256+h]*phT[b][l][h]
//       blk [512,1024) = softmax/w kernel -> wbuf (bf16), wc
// =======================================================================
__global__ __launch_bounds__(256) void k_wG(
    const unsigned short* __restrict__ LWT, const unsigned short* __restrict__ phT,
    const float* __restrict__ dur, const float* __restrict__ sk,
    const int* __restrict__ frame_len, const float* __restrict__ hw,
    const float* __restrict__ hc, const float* __restrict__ mlpWw,
    const float* __restrict__ mlpbw, const float* __restrict__ mlpWc,
    const float* __restrict__ mlpbc, unsigned short* __restrict__ G,
    unsigned short* __restrict__ wout, float* __restrict__ wcout) {
  __shared__ __align__(16) char smem[15360];
  int blk = blockIdx.x;
  int tid = threadIdx.x, wave = tid >> 6, lane = tid & 63;
  if (blk < 512) {
    int x = blk & 7, q = (blk >> 3) & 3, b = blk >> 5;
    int o0 = (x >> 1) * 64, l0 = (x & 1) * 128;
    int quad = lane >> 4, col = lane & 15;
    unsigned short* Asm = (unsigned short*)smem;        // 64*40
    unsigned short* Bsm = Asm + 64 * 40;                // 128*40
    int arow = wave * 16 + (lane >> 2);
    int aseg = lane & 3;
    const unsigned short* Ag = LWT + (size_t)(o0 + arow) * 1024 + q * 256 + aseg * 8;
    unsigned short* Al = Asm + arow * 40 + aseg * 8;
    int brow = wave * 32 + (lane >> 2);
    const unsigned short* Bg0 =
        phT + (size_t)b * 65536 + (size_t)(l0 + brow) * 256 + aseg * 8;
    const unsigned short* Bg1 = Bg0 + 16 * 256;
    unsigned short* Bl0 = Bsm + brow * 40 + aseg * 8;
    unsigned short* Bl1 = Bl0 + 16 * 40;
    int wm = (wave & 1) * 32, wn = (wave >> 1) * 64;
    f4 acc[2][4] = {};
    uint4 ra = *(const uint4*)Ag;
    uint4 rb0 = *(const uint4*)Bg0;
    uint4 rb1 = *(const uint4*)Bg1;
    for (int k0 = 0; k0 < 256; k0 += 32) {
      __syncthreads();
      *(uint4*)Al = ra;
      *(uint4*)Bl0 = rb0;
      *(uint4*)Bl1 = rb1;
      __syncthreads();
      if (k0 + 32 < 256) {
        ra = *(const uint4*)(Ag + k0 + 32);
        rb0 = *(const uint4*)(Bg0 + k0 + 32);
        rb1 = *(const uint4*)(Bg1 + k0 + 32);
      }
      v8s af[2], bf[4];
#pragma unroll
      for (int mt = 0; mt < 2; mt++)
        af[mt] = *(const v8s*)(Asm + (wm + mt * 16 + col) * 40 + quad * 8);
#pragma unroll
      for (int nt = 0; nt < 4; nt++)
        bf[nt] = *(const v8s*)(Bsm + (wn + nt * 16 + col) * 40 + quad * 8);
#pragma unroll
      for (int mt = 0; mt < 2; mt++)
#pragma unroll
        for (int nt = 0; nt < 4; nt++)
          acc[mt][nt] = __builtin_amdgcn_mfma_f32_16x16x32_bf16(af[mt], bf[nt],
                                                                acc[mt][nt], 0, 0, 0);
    }
    int quad2 = lane >> 4, col2 = lane & 15;
#pragma unroll
    for (int mt = 0; mt < 2; mt++)
#pragma unroll
      for (int nt = 0; nt < 4; nt++)
#pragma unroll
        for (int r = 0; r < 4; r++) {
          int orow = o0 + wm + mt * 16 + quad2 * 4 + r;
          int lcol = l0 + wn + nt * 16 + col2;
          G[(size_t)b * 262144 + (size_t)orow * 1024 + q * 256 + lcol] =
              f2bf(acc[mt][nt][r]);
        }
  } else {
    int idx = blk - 512;
    int b = idx >> 5;
    int tbase = (idx & 31) * 32 + wave * 8;
    int l0 = lane * 4;
    float mw[40], mbw[4], mc[20], mbc[2];
#pragma unroll
    for (int i = 0; i < 40; i++) mw[i] = mlpWw[i];
#pragma unroll
    for (int i = 0; i < 4; i++) mbw[i] = mlpbw[i];
#pragma unroll
    for (int i = 0; i < 20; i++) mc[i] = mlpWc[i];
#pragma unroll
    for (int i = 0; i < 2; i++) mbc[i] = mlpbc[i];
    float4 dv4 = *(const float4*)&dur[b * 256 + l0];
    float4 sk4 = *(const float4*)&sk[b * 256 + l0];
    float dv[4] = {dv4.x, dv4.y, dv4.z, dv4.w};
    float skv[4] = {sk4.x, sk4.y, sk4.z, sk4.w};
    bool val[4];
#pragma unroll
    for (int j = 0; j < 4; j++) val[j] = (dv[j] != 0.f);
    float hwv[4][8], hcv[4][8];
#pragma unroll
    for (int j = 0; j < 4; j++) {
      float4 a0 = *(const float4*)&hw[((size_t)(b * 256 + l0 + j)) * 8];
      float4 a1 = *(const float4*)&hw[((size_t)(b * 256 + l0 + j)) * 8 + 4];
      float4 c0 = *(const float4*)&hc[((size_t)(b * 256 + l0 + j)) * 8];
      float4 c1 = *(const float4*)&hc[((size_t)(b * 256 + l0 + j)) * 8 + 4];
      hwv[j][0] = a0.x; hwv[j][1] = a0.y; hwv[j][2] = a0.z; hwv[j][3] = a0.w;
      hwv[j][4] = a1.x; hwv[j][5] = a1.y; hwv[j][6] = a1.z; hwv[j][7] = a1.w;
      hcv[j][0] = c0.x; hcv[j][1] = c0.y; hcv[j][2] = c0.z; hcv[j][3] = c0.w;
      hcv[j][4] = c1.x; hcv[j][5] = c1.y; hcv[j][6] = c1.z; hcv[j][7] = c1.w;
    }
    float basew[4][4], basec[4][2];
#pragma unroll
    for (int j = 0; j < 4; j++) {
#pragma unroll
      for (int q = 0; q < 4; q++) {
        float a = mbw[q] + dv[j] * mw[4 + q];
#pragma unroll
        for (int ch = 0; ch < 8; ch++) a += hwv[j][ch] * mw[(2 + ch) * 4 + q];
        basew[j][q] = a;
      }
#pragma unroll
      for (int p = 0; p < 2; p++) {
        float a = mbc[p] + dv[j] * mc[2 + p];
#pragma unroll
        for (int ch = 0; ch < 8; ch++) a += hcv[j][ch] * mc[(2 + ch) * 2 + p];
        basec[j][p] = a;
      }
    }
    int fl = frame_len[b];
    for (int i = 0; i < 8; i++) {
      int t = tbase + i;
      if (t >= 1000) break;
      size_t wbase = ((size_t)(b * 1000 + t)) * 1024;
      if (t >= fl) {
        ushort4 z = {0, 0, 0, 0};
#pragma unroll
        for (int q = 0; q < 4; q++) *(ushort4*)(wout + wbase + q * 256 + l0) = z;
        if (lane == 0) {
          float4 fz = {0.f, 0.f, 0.f, 0.f};
          *(float4*)(wcout + ((size_t)(b * 1000 + t)) * 8) = fz;
          *(float4*)(wcout + ((size_t)(b * 1000 + t)) * 8 + 4) = fz;
        }
        continue;
      }
      float S[4];
#pragma unroll
      for (int j = 0; j < 4; j++) S[j] = (float)(t + 1) - skv[j];
      float lg[4][4];
#pragma unroll
      for (int j = 0; j < 4; j++)
#pragma unroll
        for (int q = 0; q < 4; q++)
          lg[j][q] = val[j] ? swishf(basew[j][q] + S[j] * mw[q]) : -INFINITY;
      float mx[4];
#pragma unroll
      for (int q = 0; q < 4; q++) {
        float v = fmaxf(fmaxf(lg[0][q], lg[1][q]), fmaxf(lg[2][q], lg[3][q]));
#pragma unroll
        for (int m = 1; m < 64; m <<= 1) v = fmaxf(v, __shfl_xor(v, m));
        mx[q] = v;
      }
      float e[4][4];
#pragma unroll
      for (int j = 0; j < 4; j++)
#pragma unroll
        for (int q = 0; q < 4; q++)
          e[j][q] = val[j] ? __expf(lg[j][q] - mx[q]) : 0.f;
      float inv[4];
#pragma unroll
      for (int q = 0; q < 4; q++) {
        float v = (e[0][q] + e[1][q]) + (e[2][q] + e[3][q]);
#pragma unroll
        for (int m = 1; m < 64; m <<= 1) v += __shfl_xor(v, m);
        inv[q] = __builtin_amdgcn_rcpf(v);
      }
      float w[4][4];
#pragma unroll
      for (int q = 0; q < 4; q++) {
        ushort4 o4;
        w[0][q] = e[0][q] * inv[q]; w[1][q] = e[1][q] * inv[q];
        w[2][q] = e[2][q] * inv[q]; w[3][q] = e[3][q] * inv[q];
        o4.x = f2bf(w[0][q]); o4.y = f2bf(w[1][q]);
        o4.z = f2bf(w[2][q]); o4.w = f2bf(w[3][q]);
        *(ushort4*)(wout + wbase + q * 256 + l0) = o4;
      }
      float cp[4][2];
#pragma unroll
      for (int j = 0; j < 4; j++)
#pragma unroll
        for (int p = 0; p < 2; p++)
          cp[j][p] = swishf(basec[j][p] + S[j] * mc[p]);
      float pr[8];
#pragma unroll
      for (int q = 0; q < 4; q++)
#pragma unroll
        for (int p = 0; p < 2; p++) {
          float v = w[0][q] * cp[0][p] + w[1][q] * cp[1][p] +
                    w[2][q] * cp[2][p] + w[3][q] * cp[3][p];
#pragma unroll
          for (int m = 1; m < 64; m <<= 1) v += __shfl_xor(v, m);
          pr[q * 2 + p] = v;
        }
      if (lane == 0) {
        float4 lo = {pr[0], pr[1], pr[2], pr[3]};
        float4 hi = {pr[4], pr[5], pr[6], pr[7]};
        *(float4*)(wcout + ((size_t)(b * 1000 + t)) * 8) = lo;
        *(float4*)(wcout + ((size_t)(b * 1000 + t)) * 8 + 4) = hi;
      }
    }
  }
}

// =======================================================================
// K_GEMMF: out[b][t][o] = sum_kk w[b][t][kk]*G[b][o][kk] + biases + wc*LC
// grid (32, 16)
// =======================================================================
__global__ __launch_bounds__(256) void k_gemmF(const unsigned short* __restrict__ wbuf,
                                               const unsigned short* __restrict__ G,
                                               const float* __restrict__ lwb,
                                               const float* __restrict__ lcb,
                                               const float* __restrict__ LC,
                                               const float* __restrict__ wc,
                                               float* __restrict__ out) {
  int b = blockIdx.y;
  int t0 = (blockIdx.x >> 1) * 64;
  int o0 = (blockIdx.x & 1) * 128;
  int tid = threadIdx.x, wave = tid >> 6, lane = tid & 63;
  int quad = lane >> 4, col = lane & 15;
  __shared__ __align__(16) unsigned short Asm[64 * 40];
  __shared__ __align__(16) unsigned short Bsm[128 * 40];
  __shared__ float bias_s[128];
  __shared__ float lcs[8][128];
  __shared__ float wcs[64][8];

  for (int i = tid; i < 128; i += 256) bias_s[i] = lwb[o0 + i] + lcb[o0 + i];
  for (int i = tid; i < 1024; i += 256)
    lcs[i >> 7][i & 127] = LC[(i >> 7) * 256 + o0 + (i & 127)];
  for (int i = tid; i < 512; i += 256) {
    int r = i >> 3, j = i & 7;
    int t = t0 + r;
    wcs[r][j] = (t < 1000) ? wc[((size_t)(b * 1000 + t)) * 8 + j] : 0.f;
  }

  int arow = wave * 16 + (lane >> 2);
  int aseg = lane & 3;
  const unsigned short* Ag =
      wbuf + (size_t)b * 1024000 + (size_t)(t0 + arow) * 1024 + aseg * 8;
  unsigned short* Al = Asm + arow * 40 + aseg * 8;
  int brow = wave * 32 + (lane >> 2);
  const unsigned short* Bg0 =
      G + (size_t)b * 262144 + (size_t)(o0 + brow) * 1024 + aseg * 8;
  const unsigned short* Bg1 = Bg0 + 16 * 1024;
  unsigned short* Bl0 = Bsm + brow * 40 + aseg * 8;
  unsigned short* Bl1 = Bl0 + 16 * 40;

  int wm = (wave & 1) * 32, wn = (wave >> 1) * 64;
  f4 acc[2][4] = {};
  uint4 ra = *(const uint4*)Ag;
  uint4 rb0 = *(const uint4*)Bg0;
  uint4 rb1 = *(const uint4*)Bg1;
  for (int k0 = 0; k0 < 1024; k0 += 32) {
    __syncthreads();
    *(uint4*)Al = ra;
    *(uint4*)Bl0 = rb0;
    *(uint4*)Bl1 = rb1;
    __syncthreads();
    if (k0 + 32 < 1024) {
      ra = *(const uint4*)(Ag + k0 + 32);
      rb0 = *(const uint4*)(Bg0 + k0 + 32);
      rb1 = *(const uint4*)(Bg1 + k0 + 32);
    }
    v8s af[2], bf[4];
#pragma unroll
    for (int mt = 0; mt < 2; mt++)
      af[mt] = *(const v8s*)(Asm + (wm + mt * 16 + col) * 40 + quad * 8);
#pragma unroll
    for (int nt = 0; nt < 4; nt++)
      bf[nt] = *(const v8s*)(Bsm + (wn + nt * 16 + col) * 40 + quad * 8);
#pragma unroll
    for (int mt = 0; mt < 2; mt++)
#pragma unroll
      for (int nt = 0; nt < 4; nt++)
        acc[mt][nt] = __builtin_amdgcn_mfma_f32_16x16x32_bf16(af[mt], bf[nt],
                                                              acc[mt][nt], 0, 0, 0);
  }
#pragma unroll
  for (int mt = 0; mt < 2; mt++)
#pragma unroll
    for (int r = 0; r < 4; r++) {
      int lrow = wm + mt * 16 + quad * 4 + r;
      int trow = t0 + lrow;
      if (trow < 1000) {
        float wcl[8];
        float4 wa = *(const float4*)&wcs[lrow][0];
        float4 wb = *(const float4*)&wcs[lrow][4];
        wcl[0] = wa.x; wcl[1] = wa.y; wcl[2] = wa.z; wcl[3] = wa.w;
        wcl[4] = wb.x; wcl[5] = wb.y; wcl[6] = wb.z; wcl[7] = wb.w;
#pragma unroll
        for (int nt = 0; nt < 4; nt++) {
          int oc = wn + nt * 16 + col;
          float v = acc[mt][nt][r] + bias_s[oc];
#pragma unroll
          for (int jj = 0; jj < 8; jj++) v = fmaf(wcl[jj], lcs[jj][oc], v);
          out[((size_t)(b * 1000 + trow)) * 256 + o0 + oc] = v;
        }
      }
    }
}

// ---------- launch ----------
extern "C" void kernel_launch(void* const* d_in, const int* in_sizes, int n_in,
                              void* d_out, int out_size, void* d_ws, size_t ws_size,
                              hipStream_t stream) {
  const float* dur  = (const float*)d_in[0];
  const float* ph   = (const float*)d_in[1];
  const float* pjWw = (const float*)d_in[3];
  const float* pjbw = (const float*)d_in[4];
  const float* cvWw = (const float*)d_in[5];
  const float* cvbw = (const float*)d_in[6];
  const float* mlWw = (const float*)d_in[7];
  const float* mlbw = (const float*)d_in[8];
  const float* liWw = (const float*)d_in[9];
  const float* libw = (const float*)d_in[10];
  const float* pjWc = (const float*)d_in[11];
  const float* pjbc = (const float*)d_in[12];
  const float* cvWc = (const float*)d_in[13];
  const float* cvbc = (const float*)d_in[14];
  const float* mlWc = (const float*)d_in[15];
  const float* mlbc = (const float*)d_in[16];
  const float* liWc = (const float*)d_in[17];
  const float* libc = (const float*)d_in[18];
  float* out = (float*)d_out;

  float* f = (float*)d_ws;
  size_t o = 0;
  float* sk = f + o;            o += 4096;
  int* fl = (int*)(f + o);      o += 16;
  float* bK = f + o;            o += 64;
  unsigned short* Mb = (unsigned short*)(f + o); o += 6144;     // 48*256 bf16
  float* hw = f + o;            o += 16 * 256 * 8;
  float* hc = f + o;            o += 16 * 256 * 8;
  float* wc = f + o;            o += 16 * 1000 * 8;
  unsigned short* wbuf = (unsigned short*)(f + o); o += 8224768;
  unsigned short* G    = (unsigned short*)(f + o); o += 2097152;
  unsigned short* phT  = (unsigned short*)(f + o); o += 524288;
  unsigned short* LWT  = (unsigned short*)(f + o); o += 131072;

  k_prep<<<1344, 256, 0, stream>>>(dur, ph, liWw, cvWw, pjWw, pjbw, cvWc, pjWc,
                                   pjbc, sk, fl, Mb, bK, LWT, phT);
  k_conv<<<16, 256, 0, stream>>>(phT, Mb, bK, cvbw, cvbc, dur, hw, hc);
  k_wG<<<1024, 256, 0, stream>>>(LWT, phT, dur, sk, fl, hw, hc, mlWw, mlbw,
                                 mlWc, mlbc, G, wbuf, wc);
  k_gemmF<<<dim3(32, 16), 256, 0, stream>>>(wbuf, G, libw, libc, liWc, wc, out);
}